// Round 1
// 493.332 us; speedup vs baseline: 1.0723x; 1.0723x over previous
//
#include <hip/hip_runtime.h>
#include <math.h>
#include <float.h>

#define BLK 256

// ---------------------------------------------------------------------------
// K0: fast exclusive scan of both count arrays. One block, 1024 threads.
// ---------------------------------------------------------------------------
__device__ __forceinline__ void scan_one(const int* __restrict__ cnt, int n,
                                         int* __restrict__ starts, int* wsum)
{
    const int t = threadIdx.x;
    const int chunk = (n + 1023) / 1024;
    const int base = t * chunk;

    int sum = 0;
    for (int k = 0; k < chunk; k++) {
        int idx = base + k;
        if (idx < n) sum += cnt[idx];
    }

    const int lane = t & 63, wid = t >> 6;
    int v = sum;
#pragma unroll
    for (int off = 1; off < 64; off <<= 1) {
        int y = __shfl_up(v, off);
        if (lane >= off) v += y;
    }
    if (lane == 63) wsum[wid] = v;
    __syncthreads();
    if (wid == 0) {
        int w = (lane < 16) ? wsum[lane] : 0;
#pragma unroll
        for (int off = 1; off < 16; off <<= 1) {
            int y = __shfl_up(w, off);
            if (lane >= off) w += y;
        }
        if (lane < 16) wsum[lane] = w;
    }
    __syncthreads();

    int thr_excl = ((wid > 0) ? wsum[wid - 1] : 0) + v - sum;
    int run = thr_excl;
    for (int k = 0; k < chunk; k++) {
        int idx = base + k;
        if (idx < n) { starts[idx] = run; run += cnt[idx]; }
    }
    if (t == 0) starts[n] = wsum[15];
    __syncthreads();
}

__global__ __launch_bounds__(1024) void scan2_kernel(
    const int* __restrict__ dag_cnt, int nd,
    const int* __restrict__ obs_cnt, int no,
    int* __restrict__ dag_starts, int* __restrict__ obs_starts)
{
    __shared__ int wsum[16];
    scan_one(dag_cnt, nd, dag_starts, wsum);
    scan_one(obs_cnt, no, obs_starts, wsum);
}

// ---------------------------------------------------------------------------
// K1: expand segment ids to per-node arrays (one block per segment).
// ---------------------------------------------------------------------------
__global__ __launch_bounds__(128) void expand_ids_kernel(
    const int* __restrict__ dag_starts, int nd,
    const int* __restrict__ obs_starts, int no,
    int* __restrict__ dag_ids, int* __restrict__ obs_ids)
{
    int seg = blockIdx.x;
    if (seg < nd) {
        int s = dag_starts[seg], e = dag_starts[seg + 1];
        for (int i = s + threadIdx.x; i < e; i += 128) dag_ids[i] = seg;
    } else {
        int g = seg - nd;
        int s = obs_starts[g], e = obs_starts[g + 1];
        for (int i = s + threadIdx.x; i < e; i += 128) obs_ids[i] = g;
    }
}

// ---------------------------------------------------------------------------
// K2: per-segment layer-1 partials (dag rows 37..68 no bias; glob rows 69..100 +b1).
// ---------------------------------------------------------------------------
__global__ __launch_bounds__(256) void seg_h1_kernel(
    const float* __restrict__ dag_sum, int nd,
    const float* __restrict__ glob_sum, int no,
    const float* __restrict__ W1, const float* __restrict__ b1,
    float* __restrict__ dag_h1, float* __restrict__ glob_h1)
{
    __shared__ float Wd[32 * 32];
    __shared__ float Wg[32 * 32];
    for (int t = threadIdx.x; t < 32 * 32; t += 256) {
        int k = t / 32, j = t % 32;
        Wd[t] = W1[(size_t)(37 + k) * 32 + j];
        Wg[t] = W1[(size_t)(69 + k) * 32 + j];
    }
    __syncthreads();

    int gid = blockIdx.x * 256 + threadIdx.x;
    int seg = gid / 32;
    int j   = gid % 32;
    if (seg >= nd + no) return;

    const float* srow;
    const float* Wl;
    float acc;
    float* outp;
    if (seg < nd) {
        srow = dag_sum + (size_t)seg * 32;
        Wl = Wd; acc = 0.f;
        outp = dag_h1 + (size_t)seg * 32 + j;
    } else {
        srow = glob_sum + (size_t)(seg - nd) * 32;
        Wl = Wg; acc = b1[j];
        outp = glob_h1 + (size_t)(seg - nd) * 32 + j;
    }
#pragma unroll
    for (int k = 0; k < 32; k++)
        acc = fmaf(srow[k], Wl[k * 32 + j], acc);
    *outp = acc;
}

// ---------------------------------------------------------------------------
// K3: main MLP. ONE node per thread, NO grid-stride loop.
// Weights are wave-uniform -> read DIRECTLY from global with compile-time
// indices so the backend emits s_load into SGPRs (uniform + restrict/noclobber).
// v_fmac_f32 takes the weight as its single SGPR operand. This removes all
// ~456 ds_read_b128 per wave (the former bottleneck: per-CU DS pipe shared by
// 4 SIMDs was ~85% busy while VALU sat at 59%). No weight staging, no LDS
// weight arrays, one barrier only (tiny cross-wave reduction scratch).
// ---------------------------------------------------------------------------
__global__ __launch_bounds__(BLK) void mlp_score_kernel(
    const float* __restrict__ x, const float* __restrict__ emb,
    const float* __restrict__ dag_h1, const float* __restrict__ glob_h1,
    const int* __restrict__ dag_ids, const int* __restrict__ obs_ids,
    const int* __restrict__ mask,
    const float* __restrict__ W1, const float* __restrict__ W2,
    const float* __restrict__ b2, const float* __restrict__ W3,
    const float* __restrict__ b3, const float* __restrict__ W4,
    const float* __restrict__ b4,
    float* __restrict__ scores, float* __restrict__ blk_m,
    double* __restrict__ blk_s, int N)
{
    const int i0 = blockIdx.x * BLK + threadIdx.x;
    const bool valid = (i0 < N);
    const int i = valid ? i0 : (N - 1);   // clamp: loads safe, result discarded

    // --- per-node loads: ids first (gathers depend on them) ---
    const int d  = dag_ids[i];
    const int o  = obs_ids[i];
    const int mk = mask[i];

    // --- issue gathers (consumed early: they init h1, shortening live ranges) ---
    const float4* dh = (const float4*)(dag_h1 + (size_t)d * 32);
    const float4* gh = (const float4*)(glob_h1 + (size_t)o * 32);
    float4 dq0 = dh[0], dq1 = dh[1], dq2 = dh[2], dq3 = dh[3],
           dq4 = dh[4], dq5 = dh[5], dq6 = dh[6], dq7 = dh[7];
    float4 gq0 = gh[0], gq1 = gh[1], gq2 = gh[2], gq3 = gh[3],
           gq4 = gh[4], gq5 = gh[5], gq6 = gh[6], gq7 = gh[7];

    // --- x + emb loads (overlap with gather latency) ---
    const float* xr = x + (size_t)i * 5;
    float xv0 = xr[0], xv1 = xr[1], xv2 = xr[2], xv3 = xr[3], xv4 = xr[4];
    const float4* er = (const float4*)(emb + (size_t)i * 32);

    // --- layer 1: init from gathered per-segment partials (b1 inside glob_h1) ---
    float h1[32];
#pragma unroll
    for (int c = 0; c < 4; c++) {
        h1[0  + c] = ((const float*)&dq0)[c] + ((const float*)&gq0)[c];
        h1[4  + c] = ((const float*)&dq1)[c] + ((const float*)&gq1)[c];
        h1[8  + c] = ((const float*)&dq2)[c] + ((const float*)&gq2)[c];
        h1[12 + c] = ((const float*)&dq3)[c] + ((const float*)&gq3)[c];
        h1[16 + c] = ((const float*)&dq4)[c] + ((const float*)&gq4)[c];
        h1[20 + c] = ((const float*)&dq5)[c] + ((const float*)&gq5)[c];
        h1[24 + c] = ((const float*)&dq6)[c] + ((const float*)&gq6)[c];
        h1[28 + c] = ((const float*)&dq7)[c] + ((const float*)&gq7)[c];
    }

    // --- layer 1: x phase (weights from global = s_load, SGPR operand) ---
#pragma unroll
    for (int j = 0; j < 32; j++) h1[j] = fmaf(xv0, W1[j], h1[j]);
#pragma unroll
    for (int j = 0; j < 32; j++) h1[j] = fmaf(xv1, W1[32 + j], h1[j]);
#pragma unroll
    for (int j = 0; j < 32; j++) h1[j] = fmaf(xv2, W1[64 + j], h1[j]);
#pragma unroll
    for (int j = 0; j < 32; j++) h1[j] = fmaf(xv3, W1[96 + j], h1[j]);
#pragma unroll
    for (int j = 0; j < 32; j++) h1[j] = fmaf(xv4, W1[128 + j], h1[j]);

    // --- layer 1: emb phase (k = 5..36) ---
#pragma unroll
    for (int q = 0; q < 8; q++) {
        float4 e = er[q];
#pragma unroll
        for (int kk = 0; kk < 4; kk++) {
            const int k = 5 + q * 4 + kk;
            const float v = (kk == 0) ? e.x : (kk == 1) ? e.y : (kk == 2) ? e.z : e.w;
#pragma unroll
            for (int j = 0; j < 32; j++)
                h1[j] = fmaf(v, W1[k * 32 + j], h1[j]);
        }
    }
#pragma unroll
    for (int j = 0; j < 32; j++) h1[j] = fmaxf(h1[j], 0.f);

    // --- layer 2: 32 -> 16 ---
    float h2[16];
#pragma unroll
    for (int j = 0; j < 16; j++) h2[j] = b2[j];
#pragma unroll
    for (int k = 0; k < 32; k++) {
        const float v = h1[k];
#pragma unroll
        for (int j = 0; j < 16; j++)
            h2[j] = fmaf(v, W2[k * 16 + j], h2[j]);
    }
#pragma unroll
    for (int j = 0; j < 16; j++) h2[j] = fmaxf(h2[j], 0.f);

    // --- layer 3: 16 -> 8 ---
    float h3[8];
#pragma unroll
    for (int j = 0; j < 8; j++) h3[j] = b3[j];
#pragma unroll
    for (int k = 0; k < 16; k++) {
        const float v = h2[k];
#pragma unroll
        for (int j = 0; j < 8; j++)
            h3[j] = fmaf(v, W3[k * 8 + j], h3[j]);
    }
#pragma unroll
    for (int j = 0; j < 8; j++) h3[j] = fmaxf(h3[j], 0.f);

    // --- layer 4 ---
    float s = b4[0];
#pragma unroll
    for (int k = 0; k < 8; k++) s = fmaf(h3[k], W4[k], s);

    const bool live = valid && (mk != 0);
    if (valid) scores[i0] = live ? s : -FLT_MAX;

    // --- block (m, sum) merge: wave shuffle reduce, then tiny LDS merge ---
    float  m  = live ? s : -INFINITY;
    double sd = live ? 1.0 : 0.0;
#pragma unroll
    for (int off = 32; off > 0; off >>= 1) {
        float  mo = __shfl_down(m, off);
        double so = __shfl_down(sd, off);
        float M = fmaxf(m, mo);
        double out = 0.0;
        if (m  > -INFINITY) out += sd * (double)expf(m  - M);
        if (mo > -INFINITY) out += so * (double)expf(mo - M);
        m = M; sd = out;
    }
    __shared__ float  mw[BLK / 64];
    __shared__ double sw[BLK / 64];
    const int lane = threadIdx.x & 63, wid = threadIdx.x >> 6;
    if (lane == 0) { mw[wid] = m; sw[wid] = sd; }
    __syncthreads();
    if (threadIdx.x == 0) {
        float M = mw[0]; double S = sw[0];
#pragma unroll
        for (int w = 1; w < BLK / 64; w++) {
            float mb = mw[w]; double sb = sw[w];
            float Mn = fmaxf(M, mb);
            double out = 0.0;
            if (M  > -INFINITY) out += S  * (double)expf(M  - Mn);
            if (mb > -INFINITY) out += sb * (double)expf(mb - Mn);
            M = Mn; S = out;
        }
        blk_m[blockIdx.x] = M;
        blk_s[blockIdx.x] = S;
    }
}

// ---------------------------------------------------------------------------
// K4: merge per-block (m, s) pairs -> gmax, Z. One block.
// ---------------------------------------------------------------------------
__global__ __launch_bounds__(1024) void merge_kernel(
    const float* __restrict__ bm, const double* __restrict__ bs, int n,
    float* __restrict__ gmax, double* __restrict__ Z)
{
    float m = -INFINITY;
    double s = 0.0;
    for (int i = threadIdx.x; i < n; i += 1024) {
        float mb = bm[i]; double sb = bs[i];
        float M = fmaxf(m, mb);
        double out = 0.0;
        if (m  > -INFINITY) out += s  * (double)expf(m  - M);
        if (mb > -INFINITY) out += sb * (double)expf(mb - M);
        m = M; s = out;
    }
    __shared__ float  mred[1024];
    __shared__ double sred[1024];
    mred[threadIdx.x] = m;
    sred[threadIdx.x] = s;
    __syncthreads();
    for (int off = 512; off > 0; off >>= 1) {
        if (threadIdx.x < off) {
            float ma = mred[threadIdx.x], mb = mred[threadIdx.x + off];
            double sa = sred[threadIdx.x], sb = sred[threadIdx.x + off];
            float M = fmaxf(ma, mb);
            double out = 0.0;
            if (ma > -INFINITY) out += sa * (double)expf(ma - M);
            if (mb > -INFINITY) out += sb * (double)expf(mb - M);
            mred[threadIdx.x] = M;
            sred[threadIdx.x] = out;
        }
        __syncthreads();
    }
    if (threadIdx.x == 0) { *gmax = mred[0]; *Z = sred[0]; }
}

// ---------------------------------------------------------------------------
// K5: finalize out[i] = exp(s - gmax) / Z  (masked -FLT_MAX -> exactly 0).
// ---------------------------------------------------------------------------
__global__ __launch_bounds__(BLK) void finalize_kernel(
    const float* __restrict__ scores, int N,
    const float* __restrict__ gmaxp, const double* __restrict__ Zp,
    float* __restrict__ outp)
{
    const float gm = *gmaxp;
    const float rZ = (float)(1.0 / *Zp);
    int i = blockIdx.x * BLK + threadIdx.x;
    if (i < N) outp[i] = expf(scores[i] - gm) * rZ;
}

// ---------------------------------------------------------------------------
extern "C" void kernel_launch(void* const* d_in, const int* in_sizes, int n_in,
                              void* d_out, int out_size, void* d_ws, size_t ws_size,
                              hipStream_t stream)
{
    const float* x        = (const float*)d_in[0];
    const float* emb      = (const float*)d_in[1];
    const float* dag_sum  = (const float*)d_in[2];
    const float* glob_sum = (const float*)d_in[3];
    const int*   dag_cnt  = (const int*)d_in[4];
    const int*   obs_cnt  = (const int*)d_in[5];
    const int*   mask     = (const int*)d_in[6];   // bool staged as int32
    const float* W1 = (const float*)d_in[7];
    const float* b1 = (const float*)d_in[8];
    const float* W2 = (const float*)d_in[9];
    const float* b2 = (const float*)d_in[10];
    const float* W3 = (const float*)d_in[11];
    const float* b3 = (const float*)d_in[12];
    const float* W4 = (const float*)d_in[13];
    const float* b4 = (const float*)d_in[14];
    float* outp = (float*)d_out;

    const int N  = in_sizes[0] / 5;   // 2,000,000
    const int nd = in_sizes[4];       // 20,000
    const int no = in_sizes[5];       // 1,000

    const int main_blocks = (N + BLK - 1) / BLK;   // 7813

    // --- workspace layout (16B aligned slices) ---
    char* ws = (char*)d_ws;
    size_t off = 0;
    auto alloc = [&](size_t bytes) {
        void* p = ws + off;
        off += (bytes + 15) & ~(size_t)15;
        return p;
    };
    int*    dag_starts = (int*)   alloc((size_t)(nd + 1) * sizeof(int));
    int*    obs_starts = (int*)   alloc((size_t)(no + 1) * sizeof(int));
    int*    dag_ids    = (int*)   alloc((size_t)N * sizeof(int));
    int*    obs_ids    = (int*)   alloc((size_t)N * sizeof(int));
    float*  dag_h1     = (float*) alloc((size_t)nd * 32 * sizeof(float));
    float*  glob_h1    = (float*) alloc((size_t)no * 32 * sizeof(float));
    float*  scores     = (float*) alloc((size_t)N * sizeof(float));
    float*  blk_m      = (float*) alloc((size_t)main_blocks * sizeof(float));
    double* blk_s      = (double*)alloc((size_t)main_blocks * sizeof(double));
    float*  gmax       = (float*) alloc(sizeof(float));
    double* Z          = (double*)alloc(sizeof(double));
    (void)ws_size;

    // K0: prefix scans
    scan2_kernel<<<1, 1024, 0, stream>>>(dag_cnt, nd, obs_cnt, no, dag_starts, obs_starts);

    // K1: expand segment ids to nodes
    expand_ids_kernel<<<nd + no, 128, 0, stream>>>(dag_starts, nd, obs_starts, no, dag_ids, obs_ids);

    // K2: per-segment layer-1 partials
    {
        int total = (nd + no) * 32;
        seg_h1_kernel<<<(total + 255) / 256, 256, 0, stream>>>(
            dag_sum, nd, glob_sum, no, W1, b1, dag_h1, glob_h1);
    }

    // K3: main MLP + scores + per-block softmax partials
    mlp_score_kernel<<<main_blocks, BLK, 0, stream>>>(
        x, emb, dag_h1, glob_h1, dag_ids, obs_ids, mask,
        W1, W2, b2, W3, b3, W4, b4, scores, blk_m, blk_s, N);

    // K4: merge -> gmax, Z
    merge_kernel<<<1, 1024, 0, stream>>>(blk_m, blk_s, main_blocks, gmax, Z);

    // K5: finalize
    finalize_kernel<<<(N + BLK - 1) / BLK, BLK, 0, stream>>>(scores, N, gmax, Z, outp);
}